// Round 1
// baseline (504.682 us; speedup 1.0000x reference)
//
#include <hip/hip_runtime.h>

// B=2, N=2048, E=2048, H=16, D=128. All dims divisible by tiles; no bounds checks.
// Pipeline: cast fp32->bf16, q = x@Wq^T, kv = x@Wkv^T (bf16 out),
// flash attention per (b,h) with causal mask, out = y@Wout^T (fp32 out).

typedef __bf16 bf16;
typedef bf16 bf16x8 __attribute__((ext_vector_type(8)));
typedef float f32x4 __attribute__((ext_vector_type(4)));

typedef const __attribute__((address_space(1))) void cg_void;
typedef __attribute__((address_space(3))) void lds_void;

#define MFMA16(a, b, c) __builtin_amdgcn_mfma_f32_16x16x32_bf16((a), (b), (c), 0, 0, 0)

__device__ __forceinline__ void async_load16(const bf16* g, bf16* l) {
  // width-16 global->LDS DMA; LDS dest is wave-uniform base + lane*16 (linear layout only)
  __builtin_amdgcn_global_load_lds((cg_void*)g, (lds_void*)l, 16, 0, 0);
}

// ---------------- cast fp32 -> bf16, 8 elems/thread/iter ----------------
__global__ __launch_bounds__(256) void cast_bf16_kernel(const float* __restrict__ in,
                                                        bf16* __restrict__ out, int n8) {
  int i = blockIdx.x * blockDim.x + threadIdx.x;
  int stride = gridDim.x * blockDim.x;
  for (; i < n8; i += stride) {
    float4 f0 = ((const float4*)in)[2 * i];
    float4 f1 = ((const float4*)in)[2 * i + 1];
    bf16x8 o;
    o[0] = (bf16)f0.x; o[1] = (bf16)f0.y; o[2] = (bf16)f0.z; o[3] = (bf16)f0.w;
    o[4] = (bf16)f1.x; o[5] = (bf16)f1.y; o[6] = (bf16)f1.z; o[7] = (bf16)f1.w;
    ((bf16x8*)out)[i] = o;
  }
}

// ---------------- C[M,N] = A[M,K] * B[N,K]^T  (m97 structure) ----------------
// 256 threads = 4 waves, 128x128 tile, BK=32. Wave w: 64x64 subtile (2x2 wave grid),
// 4x4 MFMA tiles of 16x16x32. OutT = bf16 or float.
template <typename OutT>
__global__ __launch_bounds__(256, 2)
void gemm_bt_kernel(const bf16* __restrict__ A, const bf16* __restrict__ B,
                    OutT* __restrict__ C, int K, int NN) {
  __shared__ __attribute__((aligned(16))) bf16 As[128 * 32];
  __shared__ __attribute__((aligned(16))) bf16 Bs[128 * 32];
  const int tid = threadIdx.x;
  const int wave = tid >> 6, lane = tid & 63;
  const int quad = lane >> 4, l15 = lane & 15;
  const int m0 = blockIdx.y * 128, n0 = blockIdx.x * 128;
  const int wm = (wave >> 1) * 64, wn = (wave & 1) * 64;

  f32x4 acc[4][4];
#pragma unroll
  for (int i = 0; i < 4; ++i)
#pragma unroll
    for (int j = 0; j < 4; ++j) acc[i][j] = {0.f, 0.f, 0.f, 0.f};

  // staging: thread t covers 16B chunk t (rows 0..63) and t+256 (rows 64..127)
  const int srow = tid >> 2;
  const int scol = (tid & 3) * 8;
  const bf16* aG = A + (size_t)(m0 + srow) * K + scol;
  const bf16* bG = B + (size_t)(n0 + srow) * K + scol;
  bf16* aL = As + srow * 32 + scol;
  bf16* bL = Bs + srow * 32 + scol;
  const size_t gstep = (size_t)64 * K;

  for (int kt = 0; kt < K; kt += 32) {
    __syncthreads();  // previous iter's LDS reads done
    async_load16(aG, aL);
    async_load16(aG + gstep, aL + 64 * 32);
    async_load16(bG, bL);
    async_load16(bG + gstep, bL + 64 * 32);
    aG += 32; bG += 32;
    __syncthreads();  // drains vmcnt before barrier -> tiles visible

    bf16x8 af[4], bfr[4];
#pragma unroll
    for (int i = 0; i < 4; ++i)
      af[i] = *(const bf16x8*)(As + (wm + i * 16 + l15) * 32 + quad * 8);
#pragma unroll
    for (int j = 0; j < 4; ++j)
      bfr[j] = *(const bf16x8*)(Bs + (wn + j * 16 + l15) * 32 + quad * 8);
#pragma unroll
    for (int i = 0; i < 4; ++i)
#pragma unroll
      for (int j = 0; j < 4; ++j) acc[i][j] = MFMA16(af[i], bfr[j], acc[i][j]);
  }

  // epilogue: C/D layout col=lane&15, row=quad*4+reg
#pragma unroll
  for (int i = 0; i < 4; ++i) {
#pragma unroll
    for (int r = 0; r < 4; ++r) {
      int row = m0 + wm + i * 16 + quad * 4 + r;
      size_t base = (size_t)row * NN + n0 + wn + l15;
#pragma unroll
      for (int j = 0; j < 4; ++j) C[base + j * 16] = (OutT)acc[i][j][r];
    }
  }
}

// ---------------- flash attention, causal ----------------
// grid = (N/64, B*H). Block: 4 waves; wave w owns Q rows q0+w*16 .. +15.
// K-tile = 64. S via QK^T (MFMA, C-layout), online softmax (rows on quads,
// reduce over lane&15), P -> LDS -> A-layout, PV with V^T in padded LDS.
__global__ __launch_bounds__(256, 2)
void attn_kernel(const bf16* __restrict__ qb, const bf16* __restrict__ kvb,
                 bf16* __restrict__ yb) {
  constexpr int NSEQ = 2048, E = 2048, D = 128;
  constexpr int KSTR = 136;  // 128 + 8 pad (elems) -> conflict-spread b128 reads
  constexpr int VSTR = 72;   // 64 + 8 pad
  constexpr int PSTR = 72;
  __shared__ __attribute__((aligned(16))) bf16 Ks[64 * KSTR];
  __shared__ __attribute__((aligned(16))) bf16 Vts[128 * VSTR];
  __shared__ __attribute__((aligned(16))) bf16 Ps[4][16 * PSTR];

  const int tid = threadIdx.x;
  const int wave = tid >> 6, lane = tid & 63;
  const int quad = lane >> 4, l15 = lane & 15;
  const int qt = blockIdx.x;
  const int b = blockIdx.y >> 4, h = blockIdx.y & 15;
  const int q0 = qt * 64;
  const float scale = 0.08838834764831845f;  // 1/sqrt(128)

  // Q A-fragments: rows = l15 (m-index), k = ks*32 + quad*8 + j
  bf16x8 aq[4];
  {
    const bf16* qrow = qb + (size_t)(b * NSEQ + q0 + wave * 16 + l15) * E + h * D;
#pragma unroll
    for (int ks = 0; ks < 4; ++ks) aq[ks] = *(const bf16x8*)(qrow + ks * 32 + quad * 8);
  }

  float m_i[4], l_i[4], alpha[4];
  f32x4 accO[8];
#pragma unroll
  for (int r = 0; r < 4; ++r) { m_i[r] = -1e30f; l_i[r] = 0.f; }
#pragma unroll
  for (int dt = 0; dt < 8; ++dt) accO[dt] = {0.f, 0.f, 0.f, 0.f};

  const int row_base = q0 + wave * 16 + quad * 4;  // + r = this lane's rows (C-layout)

  for (int kt = 0; kt <= qt; ++kt) {
    __syncthreads();
    // stage K tile [64][128] row-major (padded), coalesced 16B
#pragma unroll
    for (int p = 0; p < 4; ++p) {
      int c = p * 256 + tid;
      int row = c >> 4;
      int cc = (c & 15) * 8;
      const bf16* g = kvb + (size_t)(b * NSEQ + kt * 64 + row) * (2 * E) + h * D + cc;
      *(bf16x8*)(Ks + row * KSTR + cc) = *(const bf16x8*)g;
    }
    // stage V transposed: Vts[d][j]; lane=j -> conflict-free b16 writes
#pragma unroll
    for (int p = 0; p < 4; ++p) {
      int dc = (p * 4 + wave) * 8;
      const bf16* g = kvb + (size_t)(b * NSEQ + kt * 64 + lane) * (2 * E) + E + h * D + dc;
      bf16x8 v = *(const bf16x8*)g;
#pragma unroll
      for (int i = 0; i < 8; ++i) Vts[(dc + i) * VSTR + lane] = v[i];
    }
    __syncthreads();

    // S = Q K^T (16x64 per wave)
    f32x4 s_acc[4];
#pragma unroll
    for (int j = 0; j < 4; ++j) s_acc[j] = {0.f, 0.f, 0.f, 0.f};
#pragma unroll
    for (int ks = 0; ks < 4; ++ks)
#pragma unroll
      for (int j = 0; j < 4; ++j) {
        bf16x8 bk = *(const bf16x8*)(Ks + (j * 16 + l15) * KSTR + ks * 32 + quad * 8);
        s_acc[j] = MFMA16(aq[ks], bk, s_acc[j]);
      }

    // online softmax; lane holds rows quad*4+r, cols j*16+l15
#pragma unroll
    for (int r = 0; r < 4; ++r) {
      const int grow = row_base + r;
      float sv[4];
      float mx = -1e30f;
#pragma unroll
      for (int j = 0; j < 4; ++j) {
        int gcol = kt * 64 + j * 16 + l15;
        float s = s_acc[j][r] * scale;
        if (gcol > grow) s = -1e30f;  // causal: strictly-future masked
        sv[j] = s;
        mx = fmaxf(mx, s);
      }
#pragma unroll
      for (int sh = 1; sh < 16; sh <<= 1) mx = fmaxf(mx, __shfl_xor(mx, sh));
      float mnew = fmaxf(m_i[r], mx);
      alpha[r] = __expf(m_i[r] - mnew);
      m_i[r] = mnew;
      float psum = 0.f;
#pragma unroll
      for (int j = 0; j < 4; ++j) {
        float p = __expf(sv[j] - mnew);
        psum += p;
        Ps[wave][(quad * 4 + r) * PSTR + j * 16 + l15] = (bf16)p;
      }
#pragma unroll
      for (int sh = 1; sh < 16; sh <<= 1) psum += __shfl_xor(psum, sh);
      l_i[r] = l_i[r] * alpha[r] + psum;
    }

    // rescale O, then PV (P from LDS in A-layout, V^T as B operand)
#pragma unroll
    for (int dt = 0; dt < 8; ++dt)
#pragma unroll
      for (int r = 0; r < 4; ++r) accO[dt][r] *= alpha[r];

#pragma unroll
    for (int kk = 0; kk < 2; ++kk) {
      bf16x8 ap = *(const bf16x8*)(Ps[wave] + l15 * PSTR + kk * 32 + quad * 8);
#pragma unroll
      for (int dt = 0; dt < 8; ++dt) {
        bf16x8 bv = *(const bf16x8*)(Vts + (dt * 16 + l15) * VSTR + kk * 32 + quad * 8);
        accO[dt] = MFMA16(ap, bv, accO[dt]);
      }
    }
  }

  // normalize and write merged-head layout [B*N, E] bf16
#pragma unroll
  for (int r = 0; r < 4; ++r) {
    float inv = 1.0f / l_i[r];
    size_t base = (size_t)(b * NSEQ + row_base + r) * E + h * D + l15;
#pragma unroll
    for (int dt = 0; dt < 8; ++dt) yb[base + dt * 16] = (bf16)(accO[dt][r] * inv);
  }
}

// ---------------- launch ----------------
extern "C" void kernel_launch(void* const* d_in, const int* in_sizes, int n_in,
                              void* d_out, int out_size, void* d_ws, size_t ws_size,
                              hipStream_t stream) {
  const float* x    = (const float*)d_in[0];
  const float* Wq   = (const float*)d_in[1];
  const float* Wkv  = (const float*)d_in[2];
  const float* Wout = (const float*)d_in[3];
  float* out = (float*)d_out;

  constexpr size_t NX = (size_t)2 * 2048 * 2048;  // 8388608 (x, q, y elems)
  constexpr size_t NW = (size_t)2048 * 2048;      // 4194304 (square weight elems)

  bf16* xb    = (bf16*)d_ws;
  bf16* wqb   = xb + NX;
  bf16* wkvb  = wqb + NW;
  bf16* woutb = wkvb + 2 * NW;
  bf16* q_b   = woutb + NW;
  bf16* kv_b  = q_b + NX;
  bf16* y_b   = kv_b + 2 * NX;  // total ~112 MB of ws

  cast_bf16_kernel<<<1024, 256, 0, stream>>>(x, xb, (int)(NX / 8));
  cast_bf16_kernel<<<1024, 256, 0, stream>>>(Wq, wqb, (int)(NW / 8));
  cast_bf16_kernel<<<1024, 256, 0, stream>>>(Wkv, wkvb, (int)(2 * NW / 8));
  cast_bf16_kernel<<<1024, 256, 0, stream>>>(Wout, woutb, (int)(NW / 8));

  // q = x @ Wq^T : [4096,2048]
  gemm_bt_kernel<bf16><<<dim3(2048 / 128, 4096 / 128), 256, 0, stream>>>(xb, wqb, q_b, 2048, 2048);
  // kv = x @ Wkv^T : [4096,4096]
  gemm_bt_kernel<bf16><<<dim3(4096 / 128, 4096 / 128), 256, 0, stream>>>(xb, wkvb, kv_b, 2048, 4096);
  // attention -> y [4096,2048] bf16 (merged heads)
  attn_kernel<<<dim3(2048 / 64, 2 * 16), 256, 0, stream>>>(q_b, kv_b, y_b);
  // out = y @ Wout^T : fp32
  gemm_bt_kernel<float><<<dim3(2048 / 128, 4096 / 128), 256, 0, stream>>>(y_b, woutb, out, 2048, 2048);
}